// Round 1
// baseline (89.300 us; speedup 1.0000x reference)
//
#include <hip/hip_runtime.h>

// Problem constants
constexpr int Tn = 512;   // seq len
constexpr int Bn = 4096;  // batch
constexpr int Dn = 16;    // input dim

// ---------------- DPP helpers ----------------
// row_shr:1 : dst[i] = src[i-1] within 16-lane rows (lane0 of row keeps old)
__device__ __forceinline__ float dpp_shr1(float v) {
  return __int_as_float(__builtin_amdgcn_update_dpp(
      __float_as_int(v), __float_as_int(v), 0x111, 0xf, 0xf, false));
}
// row_ror:15 : dst[i] = src[(i+1) % 16]  (rotate "up" by one lane)
__device__ __forceinline__ float dpp_rotup1(float v) {
  return __int_as_float(__builtin_amdgcn_update_dpp(
      0, __float_as_int(v), 0x12F, 0xf, 0xf, true));
}

__device__ __forceinline__ float fast_sig(float x) {
  return __builtin_amdgcn_rcpf(1.0f + __expf(-x));
}
__device__ __forceinline__ float fast_tanh(float x) {
  // tanh(x) = 1 - 2/(exp(2x)+1); saturates gracefully to +/-1 on overflow
  return fmaf(-2.0f, __builtin_amdgcn_rcpf(1.0f + __expf(2.0f * x)), 1.0f);
}

// ---------------- Kernel 1: layer-0 input projection ----------------
// xp[t][b][g] = sum_d x[b,t,d] * w_ih0[g,d] + (b_ih[0,g] + b_hh[0,g])
// Tile 64 t x 64 b per block (256 threads). Reads coalesced along t,
// LDS transpose, writes coalesced along b.
__global__ __launch_bounds__(256) void proj0_kernel(
    const float* __restrict__ x, const float* __restrict__ w_ih0,
    const float* __restrict__ b_ih, const float* __restrict__ b_hh,
    float* __restrict__ xp) {
  // row stride 260 floats (1040 B): 16B-chunk index = 65*tl + bb -> spreads
  // across bank quads (65 odd) -> conflict-free b128 LDS ops.
  __shared__ __align__(16) float tile[64 * 260];

  const int tt0 = blockIdx.x * 64;  // t tile (8)
  const int bb0 = blockIdx.y * 64;  // b tile (64)

  float w[4][16];
  float bias[4];
#pragma unroll
  for (int g = 0; g < 4; ++g) {
    bias[g] = b_ih[g] + b_hh[g];
#pragma unroll
    for (int d = 0; d < 16; ++d) w[g][d] = w_ih0[g * 16 + d];
  }

  const int tl = threadIdx.x & 63;  // local t (lane)
  const int wq = threadIdx.x >> 6;  // wave id 0..3

#pragma unroll 4
  for (int i = 0; i < 16; ++i) {
    const int bb = wq * 16 + i;
    const float4* xr = (const float4*)(x + ((size_t)(bb0 + bb) * Tn + (tt0 + tl)) * Dn);
    float4 a0 = xr[0], a1 = xr[1], a2 = xr[2], a3 = xr[3];
    float s[4];
#pragma unroll
    for (int g = 0; g < 4; ++g) {
      float acc = bias[g];
      acc = fmaf(a0.x, w[g][0], acc);  acc = fmaf(a0.y, w[g][1], acc);
      acc = fmaf(a0.z, w[g][2], acc);  acc = fmaf(a0.w, w[g][3], acc);
      acc = fmaf(a1.x, w[g][4], acc);  acc = fmaf(a1.y, w[g][5], acc);
      acc = fmaf(a1.z, w[g][6], acc);  acc = fmaf(a1.w, w[g][7], acc);
      acc = fmaf(a2.x, w[g][8], acc);  acc = fmaf(a2.y, w[g][9], acc);
      acc = fmaf(a2.z, w[g][10], acc); acc = fmaf(a2.w, w[g][11], acc);
      acc = fmaf(a3.x, w[g][12], acc); acc = fmaf(a3.y, w[g][13], acc);
      acc = fmaf(a3.z, w[g][14], acc); acc = fmaf(a3.w, w[g][15], acc);
      s[g] = acc;
    }
    *(float4*)&tile[tl * 260 + bb * 4] = make_float4(s[0], s[1], s[2], s[3]);
  }

  __syncthreads();

  const int bl = threadIdx.x & 63;  // local b (lane) for coalesced writes
  const int tq = threadIdx.x >> 6;
#pragma unroll
  for (int i = 0; i < 16; ++i) {
    const int tt = tq * 16 + i;
    float4 v = *(const float4*)&tile[tt * 260 + bl * 4];
    ((float4*)xp)[(size_t)(tt0 + tt) * Bn + (bb0 + bl)] = v;
  }
}

// ---------------- Kernel 2: layer-pipelined recurrence ----------------
// 8 lanes per batch element; lane l (l<6) runs layer l at t = tau - l.
// h hand-off between layers via DPP row_shr:1 (groups of 8 within 16-lane
// rows; the cross-group leak lands only on lg==0 which ignores h_in).
// Layer-0 xproj float4s are prefetched 4 blocks ahead (one per lane per
// 8-tick block) and delivered to lane 0 by DPP rotation.
__global__ __launch_bounds__(64) void lstm6_kernel(
    const float* __restrict__ xp, const float* __restrict__ w_ih_rest,
    const float* __restrict__ w_hh, const float* __restrict__ b_ih,
    const float* __restrict__ b_hh, float* __restrict__ out) {
  const int tid = blockIdx.x * 64 + threadIdx.x;
  const int grp = tid >> 3;  // batch element
  const int lg = tid & 7;    // pipeline lane (layer index for lg<6)
  const bool is0 = (lg == 0);

  float wih[4], whh[4], bias[4];
  const int l = (lg < 6) ? lg : 5;
#pragma unroll
  for (int g = 0; g < 4; ++g) {
    whh[g] = w_hh[l * 4 + g];
    if (lg >= 1 && lg < 6) {
      wih[g] = w_ih_rest[(l - 1) * 4 + g];
      bias[g] = b_ih[l * 4 + g] + b_hh[l * 4 + g];
    } else {
      wih[g] = 0.f;   // lane 0: bias already folded into xproj; lanes 6,7: inert
      bias[g] = 0.f;
    }
  }

  const float4* xpv = (const float4*)xp;
  auto ld = [&](int j) {
    int t = 8 * j + lg;
    t = (t > Tn - 1) ? (Tn - 1) : t;
    return xpv[(size_t)t * Bn + grp];
  };

  // prefetch pipeline, depth 4 blocks (32 ticks ahead)
  float4 pf = ld(0);
  float4 n1 = ld(1);
  float4 n2 = ld(2);
  float4 n3 = ld(3);

  float h = 0.f, c = 0.f;

#pragma unroll 2
  for (int j = 0; j < 65; ++j) {  // 65*8 = 520 ticks >= 517 needed
    const unsigned tau0 = (unsigned)(j * 8);
#pragma unroll
    for (int k = 0; k < 8; ++k) {
      const float h_in = dpp_shr1(h);  // h of layer l-1 from previous tick
      // gate pre-activations
      const float xp0 = is0 ? pf.x : fmaf(h_in, wih[0], bias[0]);
      const float xp1 = is0 ? pf.y : fmaf(h_in, wih[1], bias[1]);
      const float xp2 = is0 ? pf.z : fmaf(h_in, wih[2], bias[2]);
      const float xp3 = is0 ? pf.w : fmaf(h_in, wih[3], bias[3]);
      const float g0 = fmaf(h, whh[0], xp0);  // i
      const float g1 = fmaf(h, whh[1], xp1);  // f
      const float g2 = fmaf(h, whh[2], xp2);  // g~
      const float g3 = fmaf(h, whh[3], xp3);  // o
      const float ii = fast_sig(g0);
      const float ff = fast_sig(g1);
      const float gg = fast_tanh(g2);
      const float oo = fast_sig(g3);
      const float cn = fmaf(ff, c, ii * gg);
      const float hn = oo * fast_tanh(cn);
      // active iff 0 <= tau - lg < 512 (unsigned wrap handles tau < lg)
      const bool act = ((tau0 + (unsigned)k) - (unsigned)lg) < (unsigned)Tn;
      c = act ? cn : c;
      h = act ? hn : h;
      // rotate pf so that at tick k lane 0 holds the projection for t = tau
      pf.x = dpp_rotup1(pf.x);
      pf.y = dpp_rotup1(pf.y);
      pf.z = dpp_rotup1(pf.z);
      pf.w = dpp_rotup1(pf.w);
    }
    pf = n1; n1 = n2; n2 = n3; n3 = ld(j + 4);
  }

  if (lg == 5) out[grp] = h;  // H=1: hidden channel 0 == h itself
}

extern "C" void kernel_launch(void* const* d_in, const int* in_sizes, int n_in,
                              void* d_out, int out_size, void* d_ws, size_t ws_size,
                              hipStream_t stream) {
  (void)in_sizes; (void)n_in; (void)out_size; (void)ws_size;
  const float* x         = (const float*)d_in[0];
  const float* w_ih0     = (const float*)d_in[1];
  const float* w_ih_rest = (const float*)d_in[2];
  const float* w_hh      = (const float*)d_in[3];
  const float* b_ih      = (const float*)d_in[4];
  const float* b_hh      = (const float*)d_in[5];
  float* out = (float*)d_out;
  float* xp  = (float*)d_ws;  // [T][B][4] fp32 = 32 MB scratch

  proj0_kernel<<<dim3(8, 64), 256, 0, stream>>>(x, w_ih0, b_ih, b_hh, xp);
  lstm6_kernel<<<512, 64, 0, stream>>>(xp, w_ih_rest, w_hh, b_ih, b_hh, out);
}

// Round 2
// 78.688 us; speedup vs baseline: 1.1349x; 1.1349x over previous
//
#include <hip/hip_runtime.h>

constexpr int Tn = 512;   // seq len
constexpr int Bn = 4096;  // batch
constexpr int Dn = 16;    // input dim

// row_shr:1 within 16-lane rows: dst[i] = src[i-1]; lane0 of row keeps old.
__device__ __forceinline__ float dpp_shr1(float v) {
  return __int_as_float(__builtin_amdgcn_update_dpp(
      __float_as_int(v), __float_as_int(v), 0x111, 0xf, 0xf, false));
}
__device__ __forceinline__ float fast_sig(float x) {
  return __builtin_amdgcn_rcpf(1.0f + __expf(-x));
}
__device__ __forceinline__ float fast_tanh(float x) {
  // tanh(x) = 1 - 2/(exp(2x)+1); saturates to +/-1 on overflow/underflow
  return fmaf(-2.0f, __builtin_amdgcn_rcpf(1.0f + __expf(2.0f * x)), 1.0f);
}

// ---------------- Kernel 1: layer-0 input projection (pure streaming) -------
// xp[b][t][g] = sum_d x[b,t,d] * w_ih0[g,d] + (b_ih[0,g] + b_hh[0,g])
// One thread per (b,t): reads 64 B of x, writes one float4. No LDS.
__global__ __launch_bounds__(256) void proj0_kernel(
    const float* __restrict__ x, const float* __restrict__ w_ih0,
    const float* __restrict__ b_ih, const float* __restrict__ b_hh,
    float4* __restrict__ xp) {
  const int n = blockIdx.x * 256 + threadIdx.x;  // flat (b,t)

  float w[4][16], bias[4];
#pragma unroll
  for (int g = 0; g < 4; ++g) {
    bias[g] = b_ih[g] + b_hh[g];  // uniform -> scalar loads
#pragma unroll
    for (int d = 0; d < 16; ++d) w[g][d] = w_ih0[g * 16 + d];
  }

  const float4* xr = (const float4*)(x + (size_t)n * Dn);
  const float4 a0 = xr[0], a1 = xr[1], a2 = xr[2], a3 = xr[3];

  float s[4];
#pragma unroll
  for (int g = 0; g < 4; ++g) {
    float acc = bias[g];
    acc = fmaf(a0.x, w[g][0], acc);  acc = fmaf(a0.y, w[g][1], acc);
    acc = fmaf(a0.z, w[g][2], acc);  acc = fmaf(a0.w, w[g][3], acc);
    acc = fmaf(a1.x, w[g][4], acc);  acc = fmaf(a1.y, w[g][5], acc);
    acc = fmaf(a1.z, w[g][6], acc);  acc = fmaf(a1.w, w[g][7], acc);
    acc = fmaf(a2.x, w[g][8], acc);  acc = fmaf(a2.y, w[g][9], acc);
    acc = fmaf(a2.z, w[g][10], acc); acc = fmaf(a2.w, w[g][11], acc);
    acc = fmaf(a3.x, w[g][12], acc); acc = fmaf(a3.y, w[g][13], acc);
    acc = fmaf(a3.z, w[g][14], acc); acc = fmaf(a3.w, w[g][15], acc);
    s[g] = acc;
  }
  xp[n] = make_float4(s[0], s[1], s[2], s[3]);
}

// ---------------- Kernel 2: layer-pipelined recurrence ----------------------
// 8 lanes per batch element; lane l (<6) runs layer l at t = tau - l.
// h hand-off via DPP row_shr:1. Layer-0 projections arrive by broadcast
// loads (all 8 lanes of a group load the same float4; HW dedups), queued
// 2 blocks (16 ticks) ahead in registers.
template <bool GATED>
__device__ __forceinline__ void lstm_tick(
    float& h, float& c, const float4 q, const bool is0,
    const float wih[4], const float whh[4], const float bias[4],
    const unsigned tau, const unsigned lg) {
  const float h_in = dpp_shr1(h);
  // select off the h critical path: base known before h_in arrives
  const float b0 = is0 ? q.x : bias[0];
  const float b1 = is0 ? q.y : bias[1];
  const float b2 = is0 ? q.z : bias[2];
  const float b3 = is0 ? q.w : bias[3];
  const float g0 = fmaf(h, whh[0], fmaf(h_in, wih[0], b0));  // i
  const float g1 = fmaf(h, whh[1], fmaf(h_in, wih[1], b1));  // f
  const float g2 = fmaf(h, whh[2], fmaf(h_in, wih[2], b2));  // g~
  const float g3 = fmaf(h, whh[3], fmaf(h_in, wih[3], b3));  // o
  const float ii = fast_sig(g0);
  const float ff = fast_sig(g1);
  const float gg = fast_tanh(g2);
  const float oo = fast_sig(g3);
  const float cn = fmaf(ff, c, ii * gg);
  const float hn = oo * fast_tanh(cn);
  if (GATED) {
    const bool act = (tau - lg) < (unsigned)Tn;  // unsigned wrap handles tau<lg
    c = act ? cn : c;
    h = act ? hn : h;
  } else {
    c = cn;
    h = hn;
  }
}

__global__ __launch_bounds__(64) void lstm6_kernel(
    const float4* __restrict__ xp, const float* __restrict__ w_ih_rest,
    const float* __restrict__ w_hh, const float* __restrict__ b_ih,
    const float* __restrict__ b_hh, float* __restrict__ out) {
  const int tid = blockIdx.x * 64 + threadIdx.x;
  const int grp = tid >> 3;  // batch element
  const int lg = tid & 7;    // pipeline lane (layer for lg<6)
  const bool is0 = (lg == 0);

  float wih[4], whh[4], bias[4];
  const int l = (lg < 6) ? lg : 5;
#pragma unroll
  for (int g = 0; g < 4; ++g) {
    whh[g] = w_hh[l * 4 + g];
    if (lg >= 1 && lg < 6) {
      wih[g] = w_ih_rest[(l - 1) * 4 + g];
      bias[g] = b_ih[l * 4 + g] + b_hh[l * 4 + g];
    } else {
      wih[g] = 0.f;  // lane 0: proj already has bias; lanes 6,7 inert
      bias[g] = 0.f;
    }
  }

  const float4* xq = xp + (size_t)grp * Tn;  // xp[grp][t]

  float4 qA[8], qB[8];
#pragma unroll
  for (int k = 0; k < 8; ++k) qA[k] = xq[k];       // t = 0..7
#pragma unroll
  for (int k = 0; k < 8; ++k) qB[k] = xq[8 + k];   // t = 8..15

  float h = 0.f, c = 0.f;

  // ---- block 0 (ticks 0..7): start-gated ----
#pragma unroll
  for (int k = 0; k < 8; ++k)
    lstm_tick<true>(h, c, qA[k], is0, wih, whh, bias, (unsigned)k, (unsigned)lg);
#pragma unroll
  for (int k = 0; k < 8; ++k) qA[k] = xq[16 + k];  // for block 2

  // ---- block 1 (ticks 8..15): clean ----
#pragma unroll
  for (int k = 0; k < 8; ++k)
    lstm_tick<false>(h, c, qB[k], is0, wih, whh, bias, 0u, 0u);
#pragma unroll
  for (int k = 0; k < 8; ++k) qB[k] = xq[24 + k];  // for block 3

  // ---- blocks 2..61: clean, double-buffered ----
#pragma unroll 1
  for (int j = 2; j < 62; j += 2) {
#pragma unroll
    for (int k = 0; k < 8; ++k)
      lstm_tick<false>(h, c, qA[k], is0, wih, whh, bias, 0u, 0u);
    const int ta = 8 * (j + 2);
#pragma unroll
    for (int k = 0; k < 8; ++k) qA[k] = xq[ta + k];
#pragma unroll
    for (int k = 0; k < 8; ++k)
      lstm_tick<false>(h, c, qB[k], is0, wih, whh, bias, 0u, 0u);
    const int tb = 8 * (j + 3);
#pragma unroll
    for (int k = 0; k < 8; ++k) qB[k] = xq[tb + k];
  }

  // ---- block 62 (ticks 496..503): clean; refill qA for block 64 (clamped) --
#pragma unroll
  for (int k = 0; k < 8; ++k)
    lstm_tick<false>(h, c, qA[k], is0, wih, whh, bias, 0u, 0u);
#pragma unroll
  for (int k = 0; k < 8; ++k) qA[k] = xq[504 + k];  // t>=512 unused (gated)

  // ---- block 63 (ticks 504..511): clean ----
#pragma unroll
  for (int k = 0; k < 8; ++k)
    lstm_tick<false>(h, c, qB[k], is0, wih, whh, bias, 0u, 0u);

  // ---- block 64 (ticks 512..519): end-gated (lane l active while tau-l<512)
#pragma unroll
  for (int k = 0; k < 8; ++k)
    lstm_tick<true>(h, c, qA[k], is0, wih, whh, bias, (unsigned)(512 + k),
                    (unsigned)lg);

  if (lg == 5) out[grp] = h;  // H=1: hidden channel 0 == h
}

extern "C" void kernel_launch(void* const* d_in, const int* in_sizes, int n_in,
                              void* d_out, int out_size, void* d_ws, size_t ws_size,
                              hipStream_t stream) {
  (void)in_sizes; (void)n_in; (void)out_size; (void)ws_size;
  const float* x         = (const float*)d_in[0];
  const float* w_ih0     = (const float*)d_in[1];
  const float* w_ih_rest = (const float*)d_in[2];
  const float* w_hh      = (const float*)d_in[3];
  const float* b_ih      = (const float*)d_in[4];
  const float* b_hh      = (const float*)d_in[5];
  float* out = (float*)d_out;
  float4* xp = (float4*)d_ws;  // [B][T] float4 = 32 MB scratch

  proj0_kernel<<<(Bn * Tn) / 256, 256, 0, stream>>>(x, w_ih0, b_ih, b_hh, xp);
  lstm6_kernel<<<(Bn * 8) / 64, 64, 0, stream>>>(xp, w_ih_rest, w_hh, b_ih,
                                                 b_hh, out);
}

// Round 3
// 64.238 us; speedup vs baseline: 1.3902x; 1.2250x over previous
//
#include <hip/hip_runtime.h>

constexpr int Tn = 512;   // seq len
constexpr int Bn = 4096;  // batch
constexpr int CH = 32;    // timesteps per chunk
constexpr int NCH = Tn / CH;  // 16

// row_shr:1 within 16-lane rows: dst[i] = src[i-1]; lane0 of row keeps old.
__device__ __forceinline__ float dpp_shr1(float v) {
  return __int_as_float(__builtin_amdgcn_update_dpp(
      __float_as_int(v), __float_as_int(v), 0x111, 0xf, 0xf, false));
}
__device__ __forceinline__ float fast_sig(float x) {
  return __builtin_amdgcn_rcpf(1.0f + __expf(-x));
}
__device__ __forceinline__ float fast_tanh(float x) {
  // tanh(x) = 1 - 2/(exp(2x)+1); saturates to +/-1 on overflow/underflow
  return fmaf(-2.0f, __builtin_amdgcn_rcpf(1.0f + __expf(2.0f * x)), 1.0f);
}

// One LSTM pipeline tick. All lanes read their gate base from LDS:
// group leaders (lg==0) walk the projection tile (step=8 float4/tick),
// lanes 1..7 re-read their layer's bias entry (step=0, broadcast).
template <bool GATED>
__device__ __forceinline__ void tick(float& h, float& c, const float4*& p,
                                     int step, const float4 wih,
                                     const float4 whh, unsigned tau,
                                     unsigned lg) {
  const float4 base = *p;
  p += step;
  const float h_in = dpp_shr1(h);
  const float g0 = fmaf(h, whh.x, fmaf(h_in, wih.x, base.x));  // i
  const float g1 = fmaf(h, whh.y, fmaf(h_in, wih.y, base.y));  // f
  const float g2 = fmaf(h, whh.z, fmaf(h_in, wih.z, base.z));  // g~
  const float g3 = fmaf(h, whh.w, fmaf(h_in, wih.w, base.w));  // o
  const float ii = fast_sig(g0);
  const float ff = fast_sig(g1);
  const float gg = fast_tanh(g2);
  const float oo = fast_sig(g3);
  const float cn = fmaf(ff, c, ii * gg);
  const float hn = oo * fast_tanh(cn);
  if (GATED) {
    const bool act = (tau - lg) < (unsigned)Tn;  // unsigned wrap: tau<lg inactive
    c = act ? cn : c;
    h = act ? hn : h;
  } else {
    c = cn;
    h = hn;
  }
}

// Fused: layer-0 projection (streaming x) + 6-layer DPP-pipelined recurrence.
// 1 wave per block, 8 batch elements per wave (8 lanes each, lane=layer).
__global__ __launch_bounds__(64) void lstm_fused_kernel(
    const float* __restrict__ x, const float* __restrict__ w_ih0,
    const float* __restrict__ w_ih_rest, const float* __restrict__ w_hh,
    const float* __restrict__ b_ih, const float* __restrict__ b_hh,
    float* __restrict__ out) {
  __shared__ __align__(16) float4 bufA[CH * 8];  // [t_local][elem]
  __shared__ __align__(16) float4 bufB[CH * 8];
  __shared__ __align__(16) float4 biasT[8];      // per-layer gate bias, idx lg-1

  const int tid = threadIdx.x;
  const int b0 = blockIdx.x * 8;
  // tick-phase roles
  const int ge = tid >> 3;        // batch element (group) 0..7
  const unsigned lg = tid & 7;    // pipeline lane = layer for lg<6
  const bool is0 = (lg == 0);
  // proj-phase roles
  const int ep = tid & 7;         // element
  const int t8p = tid >> 3;       // t sub-index 0..7

  // ---- per-lane recurrence weights ----
  const int l = (lg < 6) ? (int)lg : 5;
  float4 wih = make_float4(0.f, 0.f, 0.f, 0.f);
  float4 whh = make_float4(w_hh[l * 4 + 0], w_hh[l * 4 + 1], w_hh[l * 4 + 2],
                           w_hh[l * 4 + 3]);
  if (lg >= 1 && lg < 6)
    wih = make_float4(w_ih_rest[(l - 1) * 4 + 0], w_ih_rest[(l - 1) * 4 + 1],
                      w_ih_rest[(l - 1) * 4 + 2], w_ih_rest[(l - 1) * 4 + 3]);

  // ---- bias table (lanes 1..5: layer bias; 6,7: zeros) ----
  if (tid >= 1 && tid < 8) {
    float4 bv = make_float4(0.f, 0.f, 0.f, 0.f);
    if (tid <= 5)
      bv = make_float4(b_ih[tid * 4 + 0] + b_hh[tid * 4 + 0],
                       b_ih[tid * 4 + 1] + b_hh[tid * 4 + 1],
                       b_ih[tid * 4 + 2] + b_hh[tid * 4 + 2],
                       b_ih[tid * 4 + 3] + b_hh[tid * 4 + 3]);
    biasT[tid - 1] = bv;
  }
  const float4* pbias = &biasT[is0 ? 0 : (int)(lg - 1)];

  // ---- layer-0 projection weights (uniform -> scalar regs) ----
  float w[4][16], pb[4];
#pragma unroll
  for (int g = 0; g < 4; ++g) {
    pb[g] = b_ih[g] + b_hh[g];
#pragma unroll
    for (int d = 0; d < 16; ++d) w[g][d] = w_ih0[g * 16 + d];
  }

  const float4* x4 = (const float4*)x;
  // lane reads 64 B of x for (b0+ep, t = c*CH + t8p + 8k), k=0..3
  auto LOADC = [&](float4 xs[16], int cidx) {
    const size_t base = ((size_t)(b0 + ep) * Tn + (size_t)cidx * CH + t8p) * 4;
#pragma unroll
    for (int k = 0; k < 4; ++k)
#pragma unroll
      for (int i = 0; i < 4; ++i) xs[k * 4 + i] = x4[base + (size_t)k * 32 + i];
  };
  auto PROJ = [&](const float4 xs[16], float4* dst) {
#pragma unroll
    for (int k = 0; k < 4; ++k) {
      float s0 = pb[0], s1 = pb[1], s2 = pb[2], s3 = pb[3];
#pragma unroll
      for (int i = 0; i < 4; ++i) {
        const float4 a = xs[k * 4 + i];
        s0 = fmaf(a.x, w[0][i * 4 + 0], s0); s0 = fmaf(a.y, w[0][i * 4 + 1], s0);
        s0 = fmaf(a.z, w[0][i * 4 + 2], s0); s0 = fmaf(a.w, w[0][i * 4 + 3], s0);
        s1 = fmaf(a.x, w[1][i * 4 + 0], s1); s1 = fmaf(a.y, w[1][i * 4 + 1], s1);
        s1 = fmaf(a.z, w[1][i * 4 + 2], s1); s1 = fmaf(a.w, w[1][i * 4 + 3], s1);
        s2 = fmaf(a.x, w[2][i * 4 + 0], s2); s2 = fmaf(a.y, w[2][i * 4 + 1], s2);
        s2 = fmaf(a.z, w[2][i * 4 + 2], s2); s2 = fmaf(a.w, w[2][i * 4 + 3], s2);
        s3 = fmaf(a.x, w[3][i * 4 + 0], s3); s3 = fmaf(a.y, w[3][i * 4 + 1], s3);
        s3 = fmaf(a.z, w[3][i * 4 + 2], s3); s3 = fmaf(a.w, w[3][i * 4 + 3], s3);
      }
      dst[tid + 64 * k] = make_float4(s0, s1, s2, s3);  // [(t8p+8k)*8 + ep]
    }
  };

  float h = 0.f, c = 0.f;
  float4 xs[16];

  // ---- prologue: chunk 0 projected, chunk 1 in flight ----
  LOADC(xs, 0);
  PROJ(xs, bufA);
  LOADC(xs, 1);

  // ---- chunk 0 ticks: first 8 gated (pipeline fill), rest clean ----
  {
    const float4* p = is0 ? (bufA + ge) : pbias;
    const int step = is0 ? 8 : 0;
#pragma unroll
    for (unsigned k = 0; k < 8; ++k)
      tick<true>(h, c, p, step, wih, whh, k, lg);
#pragma unroll 8
    for (int k = 8; k < CH; ++k)
      tick<false>(h, c, p, step, wih, whh, 0u, 0u);
    PROJ(xs, bufB);   // chunk 1 -> bufB
    LOADC(xs, 2);
  }

  // ---- main loop: chunks 1..15 ----
#pragma unroll 1
  for (int j = 1; j < NCH; ++j) {
    float4* bufj = (j & 1) ? bufB : bufA;
    const float4* p = is0 ? (bufj + ge) : pbias;
    const int step = is0 ? 8 : 0;
#pragma unroll 8
    for (int k = 0; k < CH; ++k)
      tick<false>(h, c, p, step, wih, whh, 0u, 0u);
    if (j < NCH - 1) PROJ(xs, (j & 1) ? bufA : bufB);  // chunk j+1
    if (j < NCH - 2) LOADC(xs, j + 2);
  }

  // ---- tail: 5 gated ticks (tau = 512..516); leaders inactive ----
  {
    const float4* p = is0 ? (bufA + ge) : pbias;  // leader value unused
#pragma unroll
    for (unsigned k = 0; k < 5; ++k)
      tick<true>(h, c, p, 0, wih, whh, 512u + k, lg);
  }

  if (lg == 5) out[b0 + ge] = h;  // H=1: hidden channel 0 == h
}

extern "C" void kernel_launch(void* const* d_in, const int* in_sizes, int n_in,
                              void* d_out, int out_size, void* d_ws, size_t ws_size,
                              hipStream_t stream) {
  (void)in_sizes; (void)n_in; (void)out_size; (void)d_ws; (void)ws_size;
  const float* x         = (const float*)d_in[0];
  const float* w_ih0     = (const float*)d_in[1];
  const float* w_ih_rest = (const float*)d_in[2];
  const float* w_hh      = (const float*)d_in[3];
  const float* b_ih      = (const float*)d_in[4];
  const float* b_hh      = (const float*)d_in[5];
  float* out = (float*)d_out;

  lstm_fused_kernel<<<Bn / 8, 64, 0, stream>>>(x, w_ih0, w_ih_rest, w_hh,
                                               b_ih, b_hh, out);
}